// Round 6
// baseline (176.545 us; speedup 1.0000x reference)
//
#include <hip/hip_runtime.h>
#include <hip/hip_bf16.h>
#include <stdint.h>

// ---------------------------------------------------------------------------
// pcnn round 16: R13 base + tap-packed layer 0 (kill the K=8/32 waste).
//  - R14/R15 post-mortem: both restructures spilled (WRITE_SIZE 16->64/98MB).
//    R13's alternating-inline structure is at ~250/256 live regs; scheduling
//    attacks are closed. This round removes WORK instead.
//  - Layer 0 had K=32 MFMAs with 8 real channels (quads 1-3 fed zeros).
//    Tap-packed: k = 8*tap_in_group + ch; quad q supplies tap q's 8 channels
//    read per-lane from LDS stage (invalid taps -> zeroed row 25).
//    3 groups {t0-3}{t4-7}{t8} x 2 M-halves, compile-time skip of empty
//    groups: layer-0 MFMAs 338 -> 130 (-8.1% of kernel total). A-frags
//    24 regs vs 72; X[25] init gone -> layer-0 pressure DROPS.
//  - B-reads pipelined one pixel ahead (named rotation, no dyn indexing).
//  - Layers 1-6, logits, colors GEMM, staging, LDS strides: identical R13.
// ---------------------------------------------------------------------------

typedef short bf16x8 __attribute__((ext_vector_type(8)));
typedef float f32x4  __attribute__((ext_vector_type(4)));

// d_ws: WALL bf16 [8 layers][9 taps][32 o(permuted rows)][32 c] @0 (73728 u16)
//   l=0: TAP-PACKED conv0 (slots t=0..2 = groups, k=8*tq+ch), l=1..6: mid,
//   l=7 rows<6: logits; l=7 rows>=6: wpost frags
// f32 @ byte 147456: BALL[8][32](permuted) @0, BP32[32] @256 (zero-padded bpost)
#define WSB_N     73728
#define WSB_EMB   6144
#define WSF_BYTE  147456
#define WSF_BALL  0
#define WSF_BP32  256

// LDS layout (bytes):
//   phase1: stage @0 (26*136*2=7072; row 25 = zeros), inpk @7072 (6144),
//           colb @13216 (1152)
//   phase2: smb @0 (25*98*4=9800; stage+inpk dead), colb persists
#define L_STAGE_STRIDE 136
#define L_INPK   7072
#define L_COLB   13216
#define L_POOL   14368
#define SMB_STRIDE 98

__device__ __forceinline__ float b2f(unsigned short u) {
  union { unsigned int u; float f; } v; v.u = ((unsigned int)u) << 16; return v.f;
}
__device__ __forceinline__ unsigned short f2b(float f) {
  union { float f; unsigned int u; } v; v.f = f;
  unsigned int r = v.u + 0x7fffu + ((v.u >> 16) & 1u);  // RNE
  return (unsigned short)(r >> 16);
}
__device__ __forceinline__ unsigned int pk2(float lo, float hi) {
  __hip_bfloat162 h = __float22bfloat162_rn(make_float2(lo, hi));
  union { __hip_bfloat162 h; unsigned int u; } v; v.h = h; return v.u;
}
__device__ __forceinline__ bool sniff_is_f32(const void* w0raw) {
  const unsigned short* q = (const unsigned short*)w0raw;
  int hits = 0;
  #pragma unroll
  for (int i = 0; i < 64; ++i) {
    unsigned int e = (q[i] >> 7) & 0xFFu;
    if (e >= 130u) ++hits;
  }
  return hits > 0;
}
__device__ __forceinline__ float ldw(const void* p, long idx, bool f32) {
  return f32 ? ((const float*)p)[idx] : b2f(((const unsigned short*)p)[idx]);
}
// C-row m -> B-k-slot permutation
__device__ __forceinline__ int kperm(int m) {
  return (m < 16) ? ((m >> 2) * 8 + (m & 3))
                  : (((m - 16) >> 2) * 8 + 4 + (m & 3));
}

// ---------------- weight pre-pack ------------------------------------------
__global__ void prep_weights(const void* __restrict__ w0,
                             const void* __restrict__ b0,
                             const void* __restrict__ wm,
                             const void* __restrict__ bm,
                             const void* __restrict__ wl,
                             const void* __restrict__ bl,
                             const void* __restrict__ wp,
                             const void* __restrict__ bp,
                             unsigned short* __restrict__ wsb,
                             float* __restrict__ wsf) {
  const bool f32 = sniff_is_f32(w0);
  int e = blockIdx.x * blockDim.x + threadIdx.x;
  if (e < WSB_N) {                        // WALL[l][t][o32][c32]
    int l = e / 9216, r = e % 9216, t = r / 1024, r2 = r % 1024;
    int o = r2 >> 5, c = r2 & 31;
    if (l == 7 && o >= 6) return;         // reserved for wpost frags
    float v = 0.f;
    if (l == 0) {
      // tap-packed: slot t<3 = group g; k = 8*tq + j; tap = g*4 + tq
      int co = kperm(o);
      if (t < 3 && co < 25) {
        int tq = c >> 3, j = c & 7, tap = t * 4 + tq;
        if (tap < 9) v = ldw(w0, (co * 8 + j) * 9 + tap, f32);
      }
    } else if (l < 7) {
      int co = kperm(o);                  // original out-channel at row o
      if (co < 25 && c < 25)
        v = ldw(wm, (((l - 1) * 25 + co) * 25 + c) * 9 + t, f32);
    } else {
      if (c < 25) v = ldw(wl, (o * 25 + c) * 9 + t, f32);
    }
    wsb[e] = f2b(v);
  } else if (e < WSB_N + WSB_EMB) {
    // wpost frag pack: conceptual [hl2][chunk3][o32][k32], physical at
    // layer-7 rows >= 6: rowidx = hl*96+chunk*32+o -> (tap, row 6+rowidx%26)
    int idx = e - WSB_N;
    int hl = idx / 3072, rem = idx % 3072;
    int chunk = rem / 1024, r2 = rem % 1024;
    int o = r2 >> 5, k = r2 & 31;
    float w = (o < 18 && k < 25) ? ldw(wp, (o * 3 + chunk) * 25 + k, f32) : 0.f;
    unsigned short hi = f2b(w);
    unsigned short val = hl ? f2b(w - b2f(hi)) : hi;
    int rowidx = hl * 96 + chunk * 32 + o;
    int t = rowidx / 26, rr = 6 + rowidx % 26;
    wsb[7 * 9216 + t * 1024 + rr * 32 + k] = val;
  } else {
    int q = e - WSB_N - WSB_EMB;
    if (q < 256) {                        // BALL[l][32] (rows permuted, l<7)
      int l = q >> 5, m = q & 31;
      float v = 0.f;
      if (l < 7) {
        int co = kperm(m);
        if (co < 25) v = (l == 0) ? ldw(b0, co, f32) : ldw(bm, (l - 1) * 25 + co, f32);
      } else {
        if (m < 6) v = ldw(bl, m, f32);
      }
      wsf[WSF_BALL + q] = v;
    } else if (q < 288) {                 // BP32: zero-padded bpost
      int oc = q - 256;
      wsf[WSF_BP32 + oc] = (oc < 18) ? ldw(bp, oc, f32) : 0.f;
    }
  }
}

// ---------------- main kernel: one wave per 16 patches ---------------------
__global__ __launch_bounds__(64)
__attribute__((amdgpu_waves_per_eu(2, 2)))
void pcnn_mfma(
    const void* __restrict__ inp,
    const void* __restrict__ w0raw,
    const unsigned short* __restrict__ wsb,
    const float* __restrict__ wsf,
    void* __restrict__ out) {
  __shared__ __align__(16) unsigned char pool[L_POOL];
  short* stage = (short*)pool;              // [26px][136] phase 1 (row25=0)
  short* inpk  = (short*)(pool + L_INPK);   // [hl2][ic3][b16][k32] phase 1
  float* colb  = (float*)(pool + L_COLB);   // [b16][18oc] both phases
  float* smb   = (float*)pool;              // [25px][98] phase 2

  const bool f32m = sniff_is_f32(w0raw);
  const int lane = threadIdx.x;         // 0..63
  const int col  = lane & 15;           // MFMA n (patch) / m-row group
  const int quad = lane >> 4;
  const long g   = blockIdx.x;          // group of 16 patches

  // ---- colors A-frags + bias: issue now, consumed after staging ----
  bf16x8 WC[2][3][2];
  #pragma unroll
  for (int hl = 0; hl < 2; ++hl)
    #pragma unroll
    for (int ch = 0; ch < 3; ++ch)
      #pragma unroll
      for (int hf = 0; hf < 2; ++hf) {
        const int rowidx = hl * 96 + ch * 32 + hf * 16 + col;
        const int t = rowidx / 26, rr = 6 + rowidx % 26;
        WC[hl][ch][hf] = *(const bf16x8*)(wsb + 7 * 9216 + t * 1024 + rr * 32 + quad * 8);
      }
  f32x4 c0 = *(const f32x4*)(wsf + WSF_BP32 + quad * 4);
  f32x4 c1 = *(const f32x4*)(wsf + WSF_BP32 + 16 + quad * 4);

  // ---- zero inpk pad slots + stage zero-row 25 ----
  for (int i = lane; i < 672; i += 64) {
    int s = 25 + i % 7, rest = i / 7;     // rest = (hl*3+ic)*16+b
    inpk[rest * 32 + s] = 0;
  }
  for (int i = lane; i < L_STAGE_STRIDE; i += 64)
    stage[25 * L_STAGE_STRIDE + i] = 0;

  // ---- stage input [b][8c][25px] -> stage[px][b*8+c] + inpk hi/lo ----
  #pragma unroll 1
  for (int c0i = 0; c0i < 3200; c0i += 1600) {
    float v[25];
    #pragma unroll
    for (int j = 0; j < 25; ++j)
      v[j] = ldw(inp, g * 3200 + c0i + j * 64 + lane, f32m);
    #pragma unroll
    for (int j = 0; j < 25; ++j) {
      const int e = c0i + j * 64 + lane;
      int b = e / 200, r = e % 200, c = r / 25, px = r % 25;
      unsigned short hi = f2b(v[j]);
      stage[px * L_STAGE_STRIDE + b * 8 + c] = hi;
      if (c < 3) {
        inpk[((0 * 3 + c) * 16 + b) * 32 + px] = hi;
        inpk[((1 * 3 + c) * 16 + b) * 32 + px] = f2b(v[j] - b2f(hi));
      }
    }
  }
  __asm__ volatile("s_waitcnt lgkmcnt(0)" ::: "memory");

  // ---- colors GEMM: 18 MFMAs, double-bf16 ----
  #pragma unroll
  for (int ch = 0; ch < 3; ++ch) {
    bf16x8 Bhi = *(const bf16x8*)(inpk + ((0 * 3 + ch) * 16 + col) * 32 + quad * 8);
    bf16x8 Blo = *(const bf16x8*)(inpk + ((1 * 3 + ch) * 16 + col) * 32 + quad * 8);
    c0 = __builtin_amdgcn_mfma_f32_16x16x32_bf16(WC[0][ch][0], Bhi, c0, 0, 0, 0);
    c0 = __builtin_amdgcn_mfma_f32_16x16x32_bf16(WC[0][ch][0], Blo, c0, 0, 0, 0);
    c0 = __builtin_amdgcn_mfma_f32_16x16x32_bf16(WC[1][ch][0], Bhi, c0, 0, 0, 0);
    c1 = __builtin_amdgcn_mfma_f32_16x16x32_bf16(WC[0][ch][1], Bhi, c1, 0, 0, 0);
    c1 = __builtin_amdgcn_mfma_f32_16x16x32_bf16(WC[0][ch][1], Blo, c1, 0, 0, 0);
    c1 = __builtin_amdgcn_mfma_f32_16x16x32_bf16(WC[1][ch][1], Bhi, c1, 0, 0, 0);
  }
  // lane (patch=col): c0 regs r -> oc quad*4+r; c1 regs -> oc 16+quad*4+r
  #pragma unroll
  for (int r = 0; r < 4; ++r) colb[col * 18 + quad * 4 + r] = c0[r];
  if (quad == 0) { colb[col * 18 + 16] = c1[0]; colb[col * 18 + 17] = c1[1]; }

  bf16x8 X[25], Y[25];

  // ---- layer 0: tap-packed (3 groups x 2 M-halves), B from LDS stage ----
  {
    const unsigned short* WA = wsb;       // layer-0 group frags at slots 0..2
    bf16x8 G0[3], G1[3];
    #pragma unroll
    for (int gq = 0; gq < 3; ++gq) {
      G0[gq] = *(const bf16x8*)(WA + gq * 1024 + col * 32 + quad * 8);
      G1[gq] = *(const bf16x8*)(WA + gq * 1024 + (16 + col) * 32 + quad * 8);
    }
    const f32x4 bias0 = *(const f32x4*)(wsf + WSF_BALL + quad * 4);
    const f32x4 bias1 = *(const f32x4*)(wsf + WSF_BALL + 16 + quad * 4);
    // per-lane tap geometry: tap = gq*4 + quad
    int tdy[3], tdx[3], tvl[3];
    #pragma unroll
    for (int gq = 0; gq < 3; ++gq) {
      int tap = gq * 4 + quad;
      tvl[gq] = (tap < 9) ? 1 : 0;
      tdy[gq] = tap / 3 - 1;
      tdx[gq] = tap % 3 - 1;
    }
    auto bload = [&](int p, int gq) -> bf16x8 {
      int py = p / 5, pxx = p % 5;
      bool ok = tvl[gq] && ((unsigned)(py + tdy[gq]) < 5u) &&
                ((unsigned)(pxx + tdx[gq]) < 5u);
      int q = ok ? (p + tdy[gq] * 5 + tdx[gq]) : 25;   // 25 = zero row
      return *(const bf16x8*)(stage + q * L_STAGE_STRIDE + col * 8);
    };
    // compile-time (after unroll): does group gq touch pixel p at all?
    auto gne = [](int p, int gq) -> bool {
      int py = p / 5, pxx = p % 5;
      for (int tq = 0; tq < 4; ++tq) {
        int tap = gq * 4 + tq;
        if (tap < 9) {
          int dy = tap / 3 - 1, dx = tap % 3 - 1;
          if ((unsigned)(py + dy) < 5u && (unsigned)(pxx + dx) < 5u) return true;
        }
      }
      return false;
    };
    f32x4 p0e, p0o, p1e, p1o;
    bf16x8 Bc0, Bc1, Bc2, Bn0, Bn1, Bn2;
    if (gne(0, 0)) Bc0 = bload(0, 0);
    if (gne(0, 1)) Bc1 = bload(0, 1);
    if (gne(0, 2)) Bc2 = bload(0, 2);
    #pragma unroll
    for (int p = 0; p < 25; ++p) {
      if (p < 24) {                       // prefetch next pixel's B-frags
        if (gne(p + 1, 0)) Bn0 = bload(p + 1, 0);
        if (gne(p + 1, 1)) Bn1 = bload(p + 1, 1);
        if (gne(p + 1, 2)) Bn2 = bload(p + 1, 2);
      }
      f32x4 a0e = bias0, a1e = bias1;
      f32x4 a0o = {0.f, 0.f, 0.f, 0.f}, a1o = {0.f, 0.f, 0.f, 0.f};
      __builtin_amdgcn_s_setprio(1);
      if (gne(p, 0)) {
        a0e = __builtin_amdgcn_mfma_f32_16x16x32_bf16(G0[0], Bc0, a0e, 0, 0, 0);
        a1e = __builtin_amdgcn_mfma_f32_16x16x32_bf16(G1[0], Bc0, a1e, 0, 0, 0);
      }
      if (gne(p, 1)) {
        a0o = __builtin_amdgcn_mfma_f32_16x16x32_bf16(G0[1], Bc1, a0o, 0, 0, 0);
        a1o = __builtin_amdgcn_mfma_f32_16x16x32_bf16(G1[1], Bc1, a1o, 0, 0, 0);
      }
      if (gne(p, 2)) {
        a0e = __builtin_amdgcn_mfma_f32_16x16x32_bf16(G0[2], Bc2, a0e, 0, 0, 0);
        a1e = __builtin_amdgcn_mfma_f32_16x16x32_bf16(G1[2], Bc2, a1e, 0, 0, 0);
      }
      __builtin_amdgcn_s_setprio(0);
      if (p > 0) {
        union { bf16x8 v; unsigned int uu[4]; } nb;
        nb.uu[0] = pk2(fmaxf(p0e[0] + p0o[0], 0.f), fmaxf(p0e[1] + p0o[1], 0.f));
        nb.uu[1] = pk2(fmaxf(p0e[2] + p0o[2], 0.f), fmaxf(p0e[3] + p0o[3], 0.f));
        nb.uu[2] = pk2(fmaxf(p1e[0] + p1o[0], 0.f), fmaxf(p1e[1] + p1o[1], 0.f));
        nb.uu[3] = pk2(fmaxf(p1e[2] + p1o[2], 0.f), fmaxf(p1e[3] + p1o[3], 0.f));
        Y[p - 1] = nb.v;
      }
      p0e = a0e; p0o = a0o; p1e = a1e; p1o = a1o;
      Bc0 = Bn0; Bc1 = Bn1; Bc2 = Bn2;    // SSA rotation
    }
    {
      union { bf16x8 v; unsigned int uu[4]; } nb;
      nb.uu[0] = pk2(fmaxf(p0e[0] + p0o[0], 0.f), fmaxf(p0e[1] + p0o[1], 0.f));
      nb.uu[1] = pk2(fmaxf(p0e[2] + p0o[2], 0.f), fmaxf(p0e[3] + p0o[3], 0.f));
      nb.uu[2] = pk2(fmaxf(p1e[0] + p1o[0], 0.f), fmaxf(p1e[1] + p1o[1], 0.f));
      nb.uu[3] = pk2(fmaxf(p1e[2] + p1o[2], 0.f), fmaxf(p1e[3] + p1o[3], 0.f));
      Y[24] = nb.v;
    }
  }

  // ---- conv layer (layers 1..6): deferred pack, identical to R13 ----
  auto conv = [&](const bf16x8 (&in)[25], bf16x8 (&outp)[25], int l) {
    const unsigned short* WA = wsb + l * 9216;
    bf16x8 A0[9], A1[9];
    #pragma unroll
    for (int t = 0; t < 9; ++t) {
      A0[t] = *(const bf16x8*)(WA + t * 1024 + col * 32 + quad * 8);
      A1[t] = *(const bf16x8*)(WA + t * 1024 + (16 + col) * 32 + quad * 8);
    }
    const f32x4 bias0 = *(const f32x4*)(wsf + WSF_BALL + l * 32 + quad * 4);
    const f32x4 bias1 = *(const f32x4*)(wsf + WSF_BALL + l * 32 + 16 + quad * 4);
    f32x4 p0e, p0o, p1e, p1o;             // previous pixel's accumulators
    #pragma unroll
    for (int p = 0; p < 25; ++p) {
      const int py = p / 5, pxx = p % 5;
      f32x4 a0e = bias0, a1e = bias1;
      f32x4 a0o = {0.f, 0.f, 0.f, 0.f}, a1o = {0.f, 0.f, 0.f, 0.f};
      __builtin_amdgcn_s_setprio(1);
      #pragma unroll
      for (int dy = -1; dy <= 1; ++dy)
        #pragma unroll
        for (int dx = -1; dx <= 1; ++dx)
          if ((unsigned)(py + dy) < 5u && (unsigned)(pxx + dx) < 5u) {
            const int t = (dy + 1) * 3 + (dx + 1);
            const int q = p + dy * 5 + dx;
            if (t & 1) {
              a0o = __builtin_amdgcn_mfma_f32_16x16x32_bf16(A0[t], in[q], a0o, 0, 0, 0);
              a1o = __builtin_amdgcn_mfma_f32_16x16x32_bf16(A1[t], in[q], a1o, 0, 0, 0);
            } else {
              a0e = __builtin_amdgcn_mfma_f32_16x16x32_bf16(A0[t], in[q], a0e, 0, 0, 0);
              a1e = __builtin_amdgcn_mfma_f32_16x16x32_bf16(A1[t], in[q], a1e, 0, 0, 0);
            }
          }
      __builtin_amdgcn_s_setprio(0);
      if (p > 0) {                        // pack PREVIOUS pixel (no stall)
        union { bf16x8 v; unsigned int uu[4]; } nb;
        nb.uu[0] = pk2(fmaxf(p0e[0] + p0o[0], 0.f), fmaxf(p0e[1] + p0o[1], 0.f));
        nb.uu[1] = pk2(fmaxf(p0e[2] + p0o[2], 0.f), fmaxf(p0e[3] + p0o[3], 0.f));
        nb.uu[2] = pk2(fmaxf(p1e[0] + p1o[0], 0.f), fmaxf(p1e[1] + p1o[1], 0.f));
        nb.uu[3] = pk2(fmaxf(p1e[2] + p1o[2], 0.f), fmaxf(p1e[3] + p1o[3], 0.f));
        outp[p - 1] = nb.v;
      }
      p0e = a0e; p0o = a0o; p1e = a1e; p1o = a1o;   // SSA-renamed, no movs
    }
    {
      union { bf16x8 v; unsigned int uu[4]; } nb;
      nb.uu[0] = pk2(fmaxf(p0e[0] + p0o[0], 0.f), fmaxf(p0e[1] + p0o[1], 0.f));
      nb.uu[1] = pk2(fmaxf(p0e[2] + p0o[2], 0.f), fmaxf(p0e[3] + p0o[3], 0.f));
      nb.uu[2] = pk2(fmaxf(p1e[0] + p1o[0], 0.f), fmaxf(p1e[1] + p1o[1], 0.f));
      nb.uu[3] = pk2(fmaxf(p1e[2] + p1o[2], 0.f), fmaxf(p1e[3] + p1o[3], 0.f));
      outp[24] = nb.v;
    }
  };

  #pragma unroll 1
  for (int i = 0; i < 3; ++i) {
    conv(Y, X, 2 * i + 1);
    conv(X, Y, 2 * i + 2);
  }
  // final hidden in Y

  // ---- logits + deferred softmax tail -> smb ----
  {
    const unsigned short* WA = wsb + 7 * 9216;
    bf16x8 A[9];
    #pragma unroll
    for (int t = 0; t < 9; ++t)
      A[t] = *(const bf16x8*)(WA + t * 1024 + col * 32 + quad * 8);
    const f32x4 biasl = *(const f32x4*)(wsf + WSF_BALL + 7 * 32 + quad * 4);
    f32x4 pa;                              // previous pixel's merged logits
    auto tail = [&](const f32x4& a, int p) {
      float l4 = __shfl_xor(a[0], 16);
      float l5 = __shfl_xor(a[1], 16);
      if (quad == 0) {
        float m = fmaxf(fmaxf(fmaxf(a[0], a[1]), fmaxf(a[2], a[3])), fmaxf(l4, l5));
        float e0 = __expf(a[0] - m), e1 = __expf(a[1] - m), e2 = __expf(a[2] - m);
        float e3 = __expf(a[3] - m), e4 = __expf(l4 - m), e5 = __expf(l5 - m);
        float inv = 1.f / (e0 + e1 + e2 + e3 + e4 + e5);
        float* sp = smb + p * SMB_STRIDE + col * 6;
        sp[0] = e0 * inv; sp[1] = e1 * inv; sp[2] = e2 * inv;
        sp[3] = e3 * inv; sp[4] = e4 * inv; sp[5] = e5 * inv;
      }
    };
    #pragma unroll
    for (int p = 0; p < 25; ++p) {
      const int py = p / 5, pxx = p % 5;
      f32x4 ae = biasl, ao = {0.f, 0.f, 0.f, 0.f};
      __builtin_amdgcn_s_setprio(1);
      #pragma unroll
      for (int dy = -1; dy <= 1; ++dy)
        #pragma unroll
        for (int dx = -1; dx <= 1; ++dx)
          if ((unsigned)(py + dy) < 5u && (unsigned)(pxx + dx) < 5u) {
            const int t = (dy + 1) * 3 + (dx + 1);
            const int q = p + dy * 5 + dx;
            if (t & 1)
              ao = __builtin_amdgcn_mfma_f32_16x16x32_bf16(A[t], Y[q], ao, 0, 0, 0);
            else
              ae = __builtin_amdgcn_mfma_f32_16x16x32_bf16(A[t], Y[q], ae, 0, 0, 0);
          }
      __builtin_amdgcn_s_setprio(0);
      if (p > 0) tail(pa, p - 1);          // softmax for PREVIOUS pixel
      f32x4 a;
      a[0] = ae[0] + ao[0]; a[1] = ae[1] + ao[1];
      a[2] = ae[2] + ao[2]; a[3] = ae[3] + ao[3];
      pa = a;
    }
    tail(pa, 24);
  }
  __asm__ volatile("s_waitcnt lgkmcnt(0)" ::: "memory");

  // ---- mix + store: out[b][c][p] = sum_w colors[b][c*6+w] * sm[p][b][w] ----
  for (int e = lane; e < 1200; e += 64) {
    int b = e / 75, r = e % 75, c = r / 25, p = r % 25;
    float v = 0.f;
    #pragma unroll
    for (int w = 0; w < 6; ++w)
      v = fmaf(colb[b * 18 + c * 6 + w], smb[p * SMB_STRIDE + b * 6 + w], v);
    const long oidx = g * 1200 + e;
    if (f32m) ((float*)out)[oidx] = v;
    else      ((unsigned short*)out)[oidx] = f2b(v);
  }
}

extern "C" void kernel_launch(void* const* d_in, const int* in_sizes, int n_in,
                              void* d_out, int out_size, void* d_ws, size_t ws_size,
                              hipStream_t stream) {
  unsigned short* wsb = (unsigned short*)d_ws;
  float* wsf = (float*)((char*)d_ws + WSF_BYTE);
  const int B = in_sizes[0] / 200;  // 32768

  const int prep_n = WSB_N + WSB_EMB + 288;  // 80160
  prep_weights<<<(prep_n + 255) / 256, 256, 0, stream>>>(
      d_in[1], d_in[2], d_in[3], d_in[4], d_in[5], d_in[6], d_in[7], d_in[8],
      wsb, wsf);
  pcnn_mfma<<<B / 16, 64, 0, stream>>>(d_in[0], d_in[1], wsb, wsf, d_out);
}

// Round 7
// 163.386 us; speedup vs baseline: 1.0805x; 1.0805x over previous
//
#include <hip/hip_runtime.h>
#include <hip/hip_bf16.h>
#include <stdint.h>

// ---------------------------------------------------------------------------
// pcnn round 17: R13 base + zero-liveness code compaction.
//  - R14/R15/R16 post-mortem: every liveness-adding restructure spills
//    (WRITE_SIZE 16->64/98/100 MB). R13 survives via X-dies-as-Y-born
//    register sharing. This round changes ONLY code layout/scheduling:
//  - conv0 folded into the rolled pair loop (wave-uniform if(i>0) guard):
//    3 inlined conv copies -> 2, ~33KB -> ~26KB straight-line code (I-fetch
//    theory: body > 32KB L1I, desynced waves thrash).
//  - Deferred pack moved INSIDE the setprio(1) region: scheduler may weave
//    prev-pixel pack VALU into current cluster's MFMA shadow.
//  - Everything else bit-identical to R13 (strides 136/98, colors GEMM,
//    deferred softmax tail, e/o chains).
//  - Tripwire: WRITE_SIZE must stay ~16.3MB, FETCH ~17MB. Jump = spill =
//    revert.
// ---------------------------------------------------------------------------

typedef short bf16x8 __attribute__((ext_vector_type(8)));
typedef float f32x4  __attribute__((ext_vector_type(4)));

// d_ws: WALL bf16 [8 layers][9 taps][32 o(permuted rows)][32 c] @0 (73728 u16)
//   l=0: conv0 (c<8), l=1..6: mid, l=7 rows<6: logits; l=7 rows>=6: wpost frags
// f32 @ byte 147456: BALL[8][32](permuted) @0, BP32[32] @256 (zero-padded bpost)
#define WSB_N     73728
#define WSB_EMB   6144
#define WSF_BYTE  147456
#define WSF_BALL  0
#define WSF_BP32  256

// LDS layout (bytes):
//   phase1: stage @0 (25*136*2=6800), inpk @6800 (6144), colb @12944 (1152)
//   phase2: smb @0 (25*98*4=9800; stage+inpk dead), colb persists
#define L_STAGE_STRIDE 136
#define L_INPK   6800
#define L_COLB   12944
#define L_POOL   14096
#define SMB_STRIDE 98

__device__ __forceinline__ float b2f(unsigned short u) {
  union { unsigned int u; float f; } v; v.u = ((unsigned int)u) << 16; return v.f;
}
__device__ __forceinline__ unsigned short f2b(float f) {
  union { float f; unsigned int u; } v; v.f = f;
  unsigned int r = v.u + 0x7fffu + ((v.u >> 16) & 1u);  // RNE
  return (unsigned short)(r >> 16);
}
__device__ __forceinline__ unsigned int pk2(float lo, float hi) {
  __hip_bfloat162 h = __float22bfloat162_rn(make_float2(lo, hi));
  union { __hip_bfloat162 h; unsigned int u; } v; v.h = h; return v.u;
}
__device__ __forceinline__ bool sniff_is_f32(const void* w0raw) {
  const unsigned short* q = (const unsigned short*)w0raw;
  int hits = 0;
  #pragma unroll
  for (int i = 0; i < 64; ++i) {
    unsigned int e = (q[i] >> 7) & 0xFFu;
    if (e >= 130u) ++hits;
  }
  return hits > 0;
}
__device__ __forceinline__ float ldw(const void* p, long idx, bool f32) {
  return f32 ? ((const float*)p)[idx] : b2f(((const unsigned short*)p)[idx]);
}
// C-row m -> B-k-slot permutation
__device__ __forceinline__ int kperm(int m) {
  return (m < 16) ? ((m >> 2) * 8 + (m & 3))
                  : (((m - 16) >> 2) * 8 + 4 + (m & 3));
}

// ---------------- weight pre-pack (identical to R12/R13, verified) ---------
__global__ void prep_weights(const void* __restrict__ w0,
                             const void* __restrict__ b0,
                             const void* __restrict__ wm,
                             const void* __restrict__ bm,
                             const void* __restrict__ wl,
                             const void* __restrict__ bl,
                             const void* __restrict__ wp,
                             const void* __restrict__ bp,
                             unsigned short* __restrict__ wsb,
                             float* __restrict__ wsf) {
  const bool f32 = sniff_is_f32(w0);
  int e = blockIdx.x * blockDim.x + threadIdx.x;
  if (e < WSB_N) {                        // WALL[l][t][o32][c32]
    int l = e / 9216, r = e % 9216, t = r / 1024, r2 = r % 1024;
    int o = r2 >> 5, c = r2 & 31;
    if (l == 7 && o >= 6) return;         // reserved for wpost frags
    float v = 0.f;
    if (l < 7) {
      int co = kperm(o);                  // original out-channel at row o
      if (co < 25) {
        if (l == 0) { if (c < 8)  v = ldw(w0, (co * 8 + c) * 9 + t, f32); }
        else        { if (c < 25) v = ldw(wm, (((l - 1) * 25 + co) * 25 + c) * 9 + t, f32); }
      }
    } else {
      if (c < 25) v = ldw(wl, (o * 25 + c) * 9 + t, f32);
    }
    wsb[e] = f2b(v);
  } else if (e < WSB_N + WSB_EMB) {
    // wpost frag pack: conceptual [hl2][chunk3][o32][k32], physical at
    // layer-7 rows >= 6: rowidx = hl*96+chunk*32+o -> (tap, row 6+rowidx%26)
    int idx = e - WSB_N;
    int hl = idx / 3072, rem = idx % 3072;
    int chunk = rem / 1024, r2 = rem % 1024;
    int o = r2 >> 5, k = r2 & 31;
    float w = (o < 18 && k < 25) ? ldw(wp, (o * 3 + chunk) * 25 + k, f32) : 0.f;
    unsigned short hi = f2b(w);
    unsigned short val = hl ? f2b(w - b2f(hi)) : hi;
    int rowidx = hl * 96 + chunk * 32 + o;
    int t = rowidx / 26, rr = 6 + rowidx % 26;
    wsb[7 * 9216 + t * 1024 + rr * 32 + k] = val;
  } else {
    int q = e - WSB_N - WSB_EMB;
    if (q < 256) {                        // BALL[l][32] (rows permuted, l<7)
      int l = q >> 5, m = q & 31;
      float v = 0.f;
      if (l < 7) {
        int co = kperm(m);
        if (co < 25) v = (l == 0) ? ldw(b0, co, f32) : ldw(bm, (l - 1) * 25 + co, f32);
      } else {
        if (m < 6) v = ldw(bl, m, f32);
      }
      wsf[WSF_BALL + q] = v;
    } else if (q < 288) {                 // BP32: zero-padded bpost
      int oc = q - 256;
      wsf[WSF_BP32 + oc] = (oc < 18) ? ldw(bp, oc, f32) : 0.f;
    }
  }
}

// ---------------- main kernel: one wave per 16 patches ---------------------
__global__ __launch_bounds__(64)
__attribute__((amdgpu_waves_per_eu(2, 2)))
void pcnn_mfma(
    const void* __restrict__ inp,
    const void* __restrict__ w0raw,
    const unsigned short* __restrict__ wsb,
    const float* __restrict__ wsf,
    void* __restrict__ out) {
  __shared__ __align__(16) unsigned char pool[L_POOL];
  short* stage = (short*)pool;              // [25px][136] phase 1
  short* inpk  = (short*)(pool + L_INPK);   // [hl2][ic3][b16][k32] phase 1
  float* colb  = (float*)(pool + L_COLB);   // [b16][18oc] both phases
  float* smb   = (float*)pool;              // [25px][98] phase 2

  const bool f32m = sniff_is_f32(w0raw);
  const int lane = threadIdx.x;         // 0..63
  const int col  = lane & 15;           // MFMA n (patch) / m-row group
  const int quad = lane >> 4;
  const long g   = blockIdx.x;          // group of 16 patches

  // ---- colors A-frags + bias: issue now, consumed after staging ----
  bf16x8 WC[2][3][2];
  #pragma unroll
  for (int hl = 0; hl < 2; ++hl)
    #pragma unroll
    for (int ch = 0; ch < 3; ++ch)
      #pragma unroll
      for (int hf = 0; hf < 2; ++hf) {
        const int rowidx = hl * 96 + ch * 32 + hf * 16 + col;
        const int t = rowidx / 26, rr = 6 + rowidx % 26;
        WC[hl][ch][hf] = *(const bf16x8*)(wsb + 7 * 9216 + t * 1024 + rr * 32 + quad * 8);
      }
  f32x4 c0 = *(const f32x4*)(wsf + WSF_BP32 + quad * 4);
  f32x4 c1 = *(const f32x4*)(wsf + WSF_BP32 + 16 + quad * 4);

  // ---- zero inpk pad slots k=25..31 (garbage NaN x 0-weight = NaN!) ----
  for (int i = lane; i < 672; i += 64) {
    int s = 25 + i % 7, rest = i / 7;     // rest = (hl*3+ic)*16+b
    inpk[rest * 32 + s] = 0;
  }

  // ---- stage input [b][8c][25px] -> stage[px][b*8+c] + inpk hi/lo ----
  #pragma unroll 1
  for (int c0i = 0; c0i < 3200; c0i += 1600) {
    float v[25];
    #pragma unroll
    for (int j = 0; j < 25; ++j)
      v[j] = ldw(inp, g * 3200 + c0i + j * 64 + lane, f32m);
    #pragma unroll
    for (int j = 0; j < 25; ++j) {
      const int e = c0i + j * 64 + lane;
      int b = e / 200, r = e % 200, c = r / 25, px = r % 25;
      unsigned short hi = f2b(v[j]);
      stage[px * L_STAGE_STRIDE + b * 8 + c] = hi;
      if (c < 3) {
        inpk[((0 * 3 + c) * 16 + b) * 32 + px] = hi;
        inpk[((1 * 3 + c) * 16 + b) * 32 + px] = f2b(v[j] - b2f(hi));
      }
    }
  }
  __asm__ volatile("s_waitcnt lgkmcnt(0)" ::: "memory");

  // ---- colors GEMM: 18 MFMAs, double-bf16 ----
  #pragma unroll
  for (int ch = 0; ch < 3; ++ch) {
    bf16x8 Bhi = *(const bf16x8*)(inpk + ((0 * 3 + ch) * 16 + col) * 32 + quad * 8);
    bf16x8 Blo = *(const bf16x8*)(inpk + ((1 * 3 + ch) * 16 + col) * 32 + quad * 8);
    c0 = __builtin_amdgcn_mfma_f32_16x16x32_bf16(WC[0][ch][0], Bhi, c0, 0, 0, 0);
    c0 = __builtin_amdgcn_mfma_f32_16x16x32_bf16(WC[0][ch][0], Blo, c0, 0, 0, 0);
    c0 = __builtin_amdgcn_mfma_f32_16x16x32_bf16(WC[1][ch][0], Bhi, c0, 0, 0, 0);
    c1 = __builtin_amdgcn_mfma_f32_16x16x32_bf16(WC[0][ch][1], Bhi, c1, 0, 0, 0);
    c1 = __builtin_amdgcn_mfma_f32_16x16x32_bf16(WC[0][ch][1], Blo, c1, 0, 0, 0);
    c1 = __builtin_amdgcn_mfma_f32_16x16x32_bf16(WC[1][ch][1], Bhi, c1, 0, 0, 0);
  }
  // lane (patch=col): c0 regs r -> oc quad*4+r; c1 regs -> oc 16+quad*4+r
  #pragma unroll
  for (int r = 0; r < 4; ++r) colb[col * 18 + quad * 4 + r] = c0[r];
  if (quad == 0) { colb[col * 18 + 16] = c1[0]; colb[col * 18 + 17] = c1[1]; }

  // ---- layer-0 B-frags: quad0 holds ch0..7, other quads zero ----
  bf16x8 X[25], Y[25];
  #pragma unroll
  for (int p = 0; p < 25; ++p) {
    union { bf16x8 v; uint4 q4; } t;
    t.q4 = make_uint4(0u, 0u, 0u, 0u);
    if (quad == 0) t.q4 = *(const uint4*)(stage + p * L_STAGE_STRIDE + col * 8);
    X[p] = t.v;
  }

  // ---- conv layer: deferred pack INSIDE the prio region ----
  auto conv = [&](const bf16x8 (&in)[25], bf16x8 (&outp)[25], int l) {
    const unsigned short* WA = wsb + l * 9216;
    bf16x8 A0[9], A1[9];
    #pragma unroll
    for (int t = 0; t < 9; ++t) {
      A0[t] = *(const bf16x8*)(WA + t * 1024 + col * 32 + quad * 8);
      A1[t] = *(const bf16x8*)(WA + t * 1024 + (16 + col) * 32 + quad * 8);
    }
    const f32x4 bias0 = *(const f32x4*)(wsf + WSF_BALL + l * 32 + quad * 4);
    const f32x4 bias1 = *(const f32x4*)(wsf + WSF_BALL + l * 32 + 16 + quad * 4);
    f32x4 p0e, p0o, p1e, p1o;             // previous pixel's accumulators
    #pragma unroll
    for (int p = 0; p < 25; ++p) {
      const int py = p / 5, pxx = p % 5;
      f32x4 a0e = bias0, a1e = bias1;
      f32x4 a0o = {0.f, 0.f, 0.f, 0.f}, a1o = {0.f, 0.f, 0.f, 0.f};
      __builtin_amdgcn_s_setprio(1);
      #pragma unroll
      for (int dy = -1; dy <= 1; ++dy)
        #pragma unroll
        for (int dx = -1; dx <= 1; ++dx)
          if ((unsigned)(py + dy) < 5u && (unsigned)(pxx + dx) < 5u) {
            const int t = (dy + 1) * 3 + (dx + 1);
            const int q = p + dy * 5 + dx;
            if (t & 1) {
              a0o = __builtin_amdgcn_mfma_f32_16x16x32_bf16(A0[t], in[q], a0o, 0, 0, 0);
              a1o = __builtin_amdgcn_mfma_f32_16x16x32_bf16(A1[t], in[q], a1o, 0, 0, 0);
            } else {
              a0e = __builtin_amdgcn_mfma_f32_16x16x32_bf16(A0[t], in[q], a0e, 0, 0, 0);
              a1e = __builtin_amdgcn_mfma_f32_16x16x32_bf16(A1[t], in[q], a1e, 0, 0, 0);
            }
          }
      if (p > 0) {                        // pack PREVIOUS pixel, in-region:
        union { bf16x8 v; unsigned int uu[4]; } nb;   // weaves into MFMA shadow
        nb.uu[0] = pk2(fmaxf(p0e[0] + p0o[0], 0.f), fmaxf(p0e[1] + p0o[1], 0.f));
        nb.uu[1] = pk2(fmaxf(p0e[2] + p0o[2], 0.f), fmaxf(p0e[3] + p0o[3], 0.f));
        nb.uu[2] = pk2(fmaxf(p1e[0] + p1o[0], 0.f), fmaxf(p1e[1] + p1o[1], 0.f));
        nb.uu[3] = pk2(fmaxf(p1e[2] + p1o[2], 0.f), fmaxf(p1e[3] + p1o[3], 0.f));
        outp[p - 1] = nb.v;
      }
      __builtin_amdgcn_s_setprio(0);
      p0e = a0e; p0o = a0o; p1e = a1e; p1o = a1o;   // SSA-renamed, no movs
    }
    {
      union { bf16x8 v; unsigned int uu[4]; } nb;
      nb.uu[0] = pk2(fmaxf(p0e[0] + p0o[0], 0.f), fmaxf(p0e[1] + p0o[1], 0.f));
      nb.uu[1] = pk2(fmaxf(p0e[2] + p0o[2], 0.f), fmaxf(p0e[3] + p0o[3], 0.f));
      nb.uu[2] = pk2(fmaxf(p1e[0] + p1o[0], 0.f), fmaxf(p1e[1] + p1o[1], 0.f));
      nb.uu[3] = pk2(fmaxf(p1e[2] + p1o[2], 0.f), fmaxf(p1e[3] + p1o[3], 0.f));
      outp[24] = nb.v;
    }
  };

  // ---- 7 layers via rolled pair loop; conv0 folded with uniform guard ----
  // i=0: conv(X,Y,0); i>0: conv(Y,X,2i-1), conv(X,Y,2i). Final hidden in Y.
  #pragma unroll 1
  for (int i = 0; i < 4; ++i) {
    if (i > 0) conv(Y, X, 2 * i - 1);
    conv(X, Y, 2 * i);
  }

  // ---- logits + deferred softmax tail -> smb (unchanged from R13) ----
  {
    const unsigned short* WA = wsb + 7 * 9216;
    bf16x8 A[9];
    #pragma unroll
    for (int t = 0; t < 9; ++t)
      A[t] = *(const bf16x8*)(WA + t * 1024 + col * 32 + quad * 8);
    const f32x4 biasl = *(const f32x4*)(wsf + WSF_BALL + 7 * 32 + quad * 4);
    f32x4 pa;                              // previous pixel's merged logits
    auto tail = [&](const f32x4& a, int p) {
      float l4 = __shfl_xor(a[0], 16);
      float l5 = __shfl_xor(a[1], 16);
      if (quad == 0) {
        float m = fmaxf(fmaxf(fmaxf(a[0], a[1]), fmaxf(a[2], a[3])), fmaxf(l4, l5));
        float e0 = __expf(a[0] - m), e1 = __expf(a[1] - m), e2 = __expf(a[2] - m);
        float e3 = __expf(a[3] - m), e4 = __expf(l4 - m), e5 = __expf(l5 - m);
        float inv = 1.f / (e0 + e1 + e2 + e3 + e4 + e5);
        float* sp = smb + p * SMB_STRIDE + col * 6;
        sp[0] = e0 * inv; sp[1] = e1 * inv; sp[2] = e2 * inv;
        sp[3] = e3 * inv; sp[4] = e4 * inv; sp[5] = e5 * inv;
      }
    };
    #pragma unroll
    for (int p = 0; p < 25; ++p) {
      const int py = p / 5, pxx = p % 5;
      f32x4 ae = biasl, ao = {0.f, 0.f, 0.f, 0.f};
      __builtin_amdgcn_s_setprio(1);
      #pragma unroll
      for (int dy = -1; dy <= 1; ++dy)
        #pragma unroll
        for (int dx = -1; dx <= 1; ++dx)
          if ((unsigned)(py + dy) < 5u && (unsigned)(pxx + dx) < 5u) {
            const int t = (dy + 1) * 3 + (dx + 1);
            const int q = p + dy * 5 + dx;
            if (t & 1)
              ao = __builtin_amdgcn_mfma_f32_16x16x32_bf16(A[t], Y[q], ao, 0, 0, 0);
            else
              ae = __builtin_amdgcn_mfma_f32_16x16x32_bf16(A[t], Y[q], ae, 0, 0, 0);
          }
      __builtin_amdgcn_s_setprio(0);
      if (p > 0) tail(pa, p - 1);          // softmax for PREVIOUS pixel
      f32x4 a;
      a[0] = ae[0] + ao[0]; a[1] = ae[1] + ao[1];
      a[2] = ae[2] + ao[2]; a[3] = ae[3] + ao[3];
      pa = a;
    }
    tail(pa, 24);
  }
  __asm__ volatile("s_waitcnt lgkmcnt(0)" ::: "memory");

  // ---- mix + store: out[b][c][p] = sum_w colors[b][c*6+w] * sm[p][b][w] ----
  for (int e = lane; e < 1200; e += 64) {
    int b = e / 75, r = e % 75, c = r / 25, p = r % 25;
    float v = 0.f;
    #pragma unroll
    for (int w = 0; w < 6; ++w)
      v = fmaf(colb[b * 18 + c * 6 + w], smb[p * SMB_STRIDE + b * 6 + w], v);
    const long oidx = g * 1200 + e;
    if (f32m) ((float*)out)[oidx] = v;
    else      ((unsigned short*)out)[oidx] = f2b(v);
  }
}

extern "C" void kernel_launch(void* const* d_in, const int* in_sizes, int n_in,
                              void* d_out, int out_size, void* d_ws, size_t ws_size,
                              hipStream_t stream) {
  unsigned short* wsb = (unsigned short*)d_ws;
  float* wsf = (float*)((char*)d_ws + WSF_BYTE);
  const int B = in_sizes[0] / 200;  // 32768

  const int prep_n = WSB_N + WSB_EMB + 288;  // 80160
  prep_weights<<<(prep_n + 255) / 256, 256, 0, stream>>>(
      d_in[1], d_in[2], d_in[3], d_in[4], d_in[5], d_in[6], d_in[7], d_in[8],
      wsb, wsf);
  pcnn_mfma<<<B / 16, 64, 0, stream>>>(d_in[0], d_in[1], wsb, wsf, d_out);
}

// Round 8
// 156.963 us; speedup vs baseline: 1.1248x; 1.0409x over previous
//
#include <hip/hip_runtime.h>
#include <hip/hip_bf16.h>
#include <stdint.h>

// ---------------------------------------------------------------------------
// pcnn round 18: R13 exact structure, setprio fences DELETED (clean A/B).
//  - R14-R17 post-mortem: four restructures, four spills. R13's exact
//    control-flow shape is the only non-spilling form at the saturated
//    2-wave/EU register budget (128 VGPR + ~128 AGPR).
//  - Remaining zero-liveness lever: the 200 s_setprio(1)/(0) pairs are
//    compiler scheduling fences pinning pack/softmax VALU BETWEEN MFMA
//    clusters (why R13's deferred pack was ~null). Both waves/SIMD are
//    phase-aligned identical code -> T5 predicts null-to-negative benefit
//    (m190). Never isolated on this kernel; this round deletes them.
//  - EVERYTHING else bit-identical to R13: conv0 separate, rolled pair
//    loop, deferred pack after cluster, strides 136/98, colors GEMM.
//  - Tripwires: WRITE~16.3MB FETCH~17MB conflicts~1.0e6 must match R13.
// ---------------------------------------------------------------------------

typedef short bf16x8 __attribute__((ext_vector_type(8)));
typedef float f32x4  __attribute__((ext_vector_type(4)));

// d_ws: WALL bf16 [8 layers][9 taps][32 o(permuted rows)][32 c] @0 (73728 u16)
//   l=0: conv0 (c<8), l=1..6: mid, l=7 rows<6: logits; l=7 rows>=6: wpost frags
// f32 @ byte 147456: BALL[8][32](permuted) @0, BP32[32] @256 (zero-padded bpost)
#define WSB_N     73728
#define WSB_EMB   6144
#define WSF_BYTE  147456
#define WSF_BALL  0
#define WSF_BP32  256

// LDS layout (bytes):
//   phase1: stage @0 (25*136*2=6800), inpk @6800 (6144), colb @12944 (1152)
//   phase2: smb @0 (25*98*4=9800; stage+inpk dead), colb persists
#define L_STAGE_STRIDE 136
#define L_INPK   6800
#define L_COLB   12944
#define L_POOL   14096
#define SMB_STRIDE 98

__device__ __forceinline__ float b2f(unsigned short u) {
  union { unsigned int u; float f; } v; v.u = ((unsigned int)u) << 16; return v.f;
}
__device__ __forceinline__ unsigned short f2b(float f) {
  union { float f; unsigned int u; } v; v.f = f;
  unsigned int r = v.u + 0x7fffu + ((v.u >> 16) & 1u);  // RNE
  return (unsigned short)(r >> 16);
}
__device__ __forceinline__ unsigned int pk2(float lo, float hi) {
  __hip_bfloat162 h = __float22bfloat162_rn(make_float2(lo, hi));
  union { __hip_bfloat162 h; unsigned int u; } v; v.h = h; return v.u;
}
__device__ __forceinline__ bool sniff_is_f32(const void* w0raw) {
  const unsigned short* q = (const unsigned short*)w0raw;
  int hits = 0;
  #pragma unroll
  for (int i = 0; i < 64; ++i) {
    unsigned int e = (q[i] >> 7) & 0xFFu;
    if (e >= 130u) ++hits;
  }
  return hits > 0;
}
__device__ __forceinline__ float ldw(const void* p, long idx, bool f32) {
  return f32 ? ((const float*)p)[idx] : b2f(((const unsigned short*)p)[idx]);
}
// C-row m -> B-k-slot permutation
__device__ __forceinline__ int kperm(int m) {
  return (m < 16) ? ((m >> 2) * 8 + (m & 3))
                  : (((m - 16) >> 2) * 8 + 4 + (m & 3));
}

// ---------------- weight pre-pack (identical to R12/R13, verified) ---------
__global__ void prep_weights(const void* __restrict__ w0,
                             const void* __restrict__ b0,
                             const void* __restrict__ wm,
                             const void* __restrict__ bm,
                             const void* __restrict__ wl,
                             const void* __restrict__ bl,
                             const void* __restrict__ wp,
                             const void* __restrict__ bp,
                             unsigned short* __restrict__ wsb,
                             float* __restrict__ wsf) {
  const bool f32 = sniff_is_f32(w0);
  int e = blockIdx.x * blockDim.x + threadIdx.x;
  if (e < WSB_N) {                        // WALL[l][t][o32][c32]
    int l = e / 9216, r = e % 9216, t = r / 1024, r2 = r % 1024;
    int o = r2 >> 5, c = r2 & 31;
    if (l == 7 && o >= 6) return;         // reserved for wpost frags
    float v = 0.f;
    if (l < 7) {
      int co = kperm(o);                  // original out-channel at row o
      if (co < 25) {
        if (l == 0) { if (c < 8)  v = ldw(w0, (co * 8 + c) * 9 + t, f32); }
        else        { if (c < 25) v = ldw(wm, (((l - 1) * 25 + co) * 25 + c) * 9 + t, f32); }
      }
    } else {
      if (c < 25) v = ldw(wl, (o * 25 + c) * 9 + t, f32);
    }
    wsb[e] = f2b(v);
  } else if (e < WSB_N + WSB_EMB) {
    // wpost frag pack: conceptual [hl2][chunk3][o32][k32], physical at
    // layer-7 rows >= 6: rowidx = hl*96+chunk*32+o -> (tap, row 6+rowidx%26)
    int idx = e - WSB_N;
    int hl = idx / 3072, rem = idx % 3072;
    int chunk = rem / 1024, r2 = rem % 1024;
    int o = r2 >> 5, k = r2 & 31;
    float w = (o < 18 && k < 25) ? ldw(wp, (o * 3 + chunk) * 25 + k, f32) : 0.f;
    unsigned short hi = f2b(w);
    unsigned short val = hl ? f2b(w - b2f(hi)) : hi;
    int rowidx = hl * 96 + chunk * 32 + o;
    int t = rowidx / 26, rr = 6 + rowidx % 26;
    wsb[7 * 9216 + t * 1024 + rr * 32 + k] = val;
  } else {
    int q = e - WSB_N - WSB_EMB;
    if (q < 256) {                        // BALL[l][32] (rows permuted, l<7)
      int l = q >> 5, m = q & 31;
      float v = 0.f;
      if (l < 7) {
        int co = kperm(m);
        if (co < 25) v = (l == 0) ? ldw(b0, co, f32) : ldw(bm, (l - 1) * 25 + co, f32);
      } else {
        if (m < 6) v = ldw(bl, m, f32);
      }
      wsf[WSF_BALL + q] = v;
    } else if (q < 288) {                 // BP32: zero-padded bpost
      int oc = q - 256;
      wsf[WSF_BP32 + oc] = (oc < 18) ? ldw(bp, oc, f32) : 0.f;
    }
  }
}

// ---------------- main kernel: one wave per 16 patches ---------------------
__global__ __launch_bounds__(64)
__attribute__((amdgpu_waves_per_eu(2, 2)))
void pcnn_mfma(
    const void* __restrict__ inp,
    const void* __restrict__ w0raw,
    const unsigned short* __restrict__ wsb,
    const float* __restrict__ wsf,
    void* __restrict__ out) {
  __shared__ __align__(16) unsigned char pool[L_POOL];
  short* stage = (short*)pool;              // [25px][136] phase 1
  short* inpk  = (short*)(pool + L_INPK);   // [hl2][ic3][b16][k32] phase 1
  float* colb  = (float*)(pool + L_COLB);   // [b16][18oc] both phases
  float* smb   = (float*)pool;              // [25px][98] phase 2

  const bool f32m = sniff_is_f32(w0raw);
  const int lane = threadIdx.x;         // 0..63
  const int col  = lane & 15;           // MFMA n (patch) / m-row group
  const int quad = lane >> 4;
  const long g   = blockIdx.x;          // group of 16 patches

  // ---- colors A-frags + bias: issue now, consumed after staging ----
  bf16x8 WC[2][3][2];
  #pragma unroll
  for (int hl = 0; hl < 2; ++hl)
    #pragma unroll
    for (int ch = 0; ch < 3; ++ch)
      #pragma unroll
      for (int hf = 0; hf < 2; ++hf) {
        const int rowidx = hl * 96 + ch * 32 + hf * 16 + col;
        const int t = rowidx / 26, rr = 6 + rowidx % 26;
        WC[hl][ch][hf] = *(const bf16x8*)(wsb + 7 * 9216 + t * 1024 + rr * 32 + quad * 8);
      }
  f32x4 c0 = *(const f32x4*)(wsf + WSF_BP32 + quad * 4);
  f32x4 c1 = *(const f32x4*)(wsf + WSF_BP32 + 16 + quad * 4);

  // ---- zero inpk pad slots k=25..31 (garbage NaN x 0-weight = NaN!) ----
  for (int i = lane; i < 672; i += 64) {
    int s = 25 + i % 7, rest = i / 7;     // rest = (hl*3+ic)*16+b
    inpk[rest * 32 + s] = 0;
  }

  // ---- stage input [b][8c][25px] -> stage[px][b*8+c] + inpk hi/lo ----
  #pragma unroll 1
  for (int c0i = 0; c0i < 3200; c0i += 1600) {
    float v[25];
    #pragma unroll
    for (int j = 0; j < 25; ++j)
      v[j] = ldw(inp, g * 3200 + c0i + j * 64 + lane, f32m);
    #pragma unroll
    for (int j = 0; j < 25; ++j) {
      const int e = c0i + j * 64 + lane;
      int b = e / 200, r = e % 200, c = r / 25, px = r % 25;
      unsigned short hi = f2b(v[j]);
      stage[px * L_STAGE_STRIDE + b * 8 + c] = hi;
      if (c < 3) {
        inpk[((0 * 3 + c) * 16 + b) * 32 + px] = hi;
        inpk[((1 * 3 + c) * 16 + b) * 32 + px] = f2b(v[j] - b2f(hi));
      }
    }
  }
  __asm__ volatile("s_waitcnt lgkmcnt(0)" ::: "memory");

  // ---- colors GEMM: 18 MFMAs, double-bf16 ----
  #pragma unroll
  for (int ch = 0; ch < 3; ++ch) {
    bf16x8 Bhi = *(const bf16x8*)(inpk + ((0 * 3 + ch) * 16 + col) * 32 + quad * 8);
    bf16x8 Blo = *(const bf16x8*)(inpk + ((1 * 3 + ch) * 16 + col) * 32 + quad * 8);
    c0 = __builtin_amdgcn_mfma_f32_16x16x32_bf16(WC[0][ch][0], Bhi, c0, 0, 0, 0);
    c0 = __builtin_amdgcn_mfma_f32_16x16x32_bf16(WC[0][ch][0], Blo, c0, 0, 0, 0);
    c0 = __builtin_amdgcn_mfma_f32_16x16x32_bf16(WC[1][ch][0], Bhi, c0, 0, 0, 0);
    c1 = __builtin_amdgcn_mfma_f32_16x16x32_bf16(WC[0][ch][1], Bhi, c1, 0, 0, 0);
    c1 = __builtin_amdgcn_mfma_f32_16x16x32_bf16(WC[0][ch][1], Blo, c1, 0, 0, 0);
    c1 = __builtin_amdgcn_mfma_f32_16x16x32_bf16(WC[1][ch][1], Bhi, c1, 0, 0, 0);
  }
  // lane (patch=col): c0 regs r -> oc quad*4+r; c1 regs -> oc 16+quad*4+r
  #pragma unroll
  for (int r = 0; r < 4; ++r) colb[col * 18 + quad * 4 + r] = c0[r];
  if (quad == 0) { colb[col * 18 + 16] = c1[0]; colb[col * 18 + 17] = c1[1]; }

  // ---- layer-0 B-frags: quad0 holds ch0..7, other quads zero ----
  bf16x8 X[25], Y[25];
  #pragma unroll
  for (int p = 0; p < 25; ++p) {
    union { bf16x8 v; uint4 q4; } t;
    t.q4 = make_uint4(0u, 0u, 0u, 0u);
    if (quad == 0) t.q4 = *(const uint4*)(stage + p * L_STAGE_STRIDE + col * 8);
    X[p] = t.v;
  }

  // ---- conv layer: deferred pack, NO setprio fences ----
  auto conv = [&](const bf16x8 (&in)[25], bf16x8 (&outp)[25], int l) {
    const unsigned short* WA = wsb + l * 9216;
    bf16x8 A0[9], A1[9];
    #pragma unroll
    for (int t = 0; t < 9; ++t) {
      A0[t] = *(const bf16x8*)(WA + t * 1024 + col * 32 + quad * 8);
      A1[t] = *(const bf16x8*)(WA + t * 1024 + (16 + col) * 32 + quad * 8);
    }
    const f32x4 bias0 = *(const f32x4*)(wsf + WSF_BALL + l * 32 + quad * 4);
    const f32x4 bias1 = *(const f32x4*)(wsf + WSF_BALL + l * 32 + 16 + quad * 4);
    f32x4 p0e, p0o, p1e, p1o;             // previous pixel's accumulators
    #pragma unroll
    for (int p = 0; p < 25; ++p) {
      const int py = p / 5, pxx = p % 5;
      f32x4 a0e = bias0, a1e = bias1;
      f32x4 a0o = {0.f, 0.f, 0.f, 0.f}, a1o = {0.f, 0.f, 0.f, 0.f};
      #pragma unroll
      for (int dy = -1; dy <= 1; ++dy)
        #pragma unroll
        for (int dx = -1; dx <= 1; ++dx)
          if ((unsigned)(py + dy) < 5u && (unsigned)(pxx + dx) < 5u) {
            const int t = (dy + 1) * 3 + (dx + 1);
            const int q = p + dy * 5 + dx;
            if (t & 1) {
              a0o = __builtin_amdgcn_mfma_f32_16x16x32_bf16(A0[t], in[q], a0o, 0, 0, 0);
              a1o = __builtin_amdgcn_mfma_f32_16x16x32_bf16(A1[t], in[q], a1o, 0, 0, 0);
            } else {
              a0e = __builtin_amdgcn_mfma_f32_16x16x32_bf16(A0[t], in[q], a0e, 0, 0, 0);
              a1e = __builtin_amdgcn_mfma_f32_16x16x32_bf16(A1[t], in[q], a1e, 0, 0, 0);
            }
          }
      if (p > 0) {                        // pack PREVIOUS pixel (no stall)
        union { bf16x8 v; unsigned int uu[4]; } nb;
        nb.uu[0] = pk2(fmaxf(p0e[0] + p0o[0], 0.f), fmaxf(p0e[1] + p0o[1], 0.f));
        nb.uu[1] = pk2(fmaxf(p0e[2] + p0o[2], 0.f), fmaxf(p0e[3] + p0o[3], 0.f));
        nb.uu[2] = pk2(fmaxf(p1e[0] + p1o[0], 0.f), fmaxf(p1e[1] + p1o[1], 0.f));
        nb.uu[3] = pk2(fmaxf(p1e[2] + p1o[2], 0.f), fmaxf(p1e[3] + p1o[3], 0.f));
        outp[p - 1] = nb.v;
      }
      p0e = a0e; p0o = a0o; p1e = a1e; p1o = a1o;   // SSA-renamed, no movs
    }
    {
      union { bf16x8 v; unsigned int uu[4]; } nb;
      nb.uu[0] = pk2(fmaxf(p0e[0] + p0o[0], 0.f), fmaxf(p0e[1] + p0o[1], 0.f));
      nb.uu[1] = pk2(fmaxf(p0e[2] + p0o[2], 0.f), fmaxf(p0e[3] + p0o[3], 0.f));
      nb.uu[2] = pk2(fmaxf(p1e[0] + p1o[0], 0.f), fmaxf(p1e[1] + p1o[1], 0.f));
      nb.uu[3] = pk2(fmaxf(p1e[2] + p1o[2], 0.f), fmaxf(p1e[3] + p1o[3], 0.f));
      outp[24] = nb.v;
    }
  };

  conv(X, Y, 0);
  #pragma unroll 1
  for (int i = 0; i < 3; ++i) {
    conv(Y, X, 2 * i + 1);
    conv(X, Y, 2 * i + 2);
  }
  // final hidden in Y

  // ---- logits + deferred softmax tail -> smb ----
  {
    const unsigned short* WA = wsb + 7 * 9216;
    bf16x8 A[9];
    #pragma unroll
    for (int t = 0; t < 9; ++t)
      A[t] = *(const bf16x8*)(WA + t * 1024 + col * 32 + quad * 8);
    const f32x4 biasl = *(const f32x4*)(wsf + WSF_BALL + 7 * 32 + quad * 4);
    f32x4 pa;                              // previous pixel's merged logits
    auto tail = [&](const f32x4& a, int p) {
      float l4 = __shfl_xor(a[0], 16);
      float l5 = __shfl_xor(a[1], 16);
      if (quad == 0) {
        float m = fmaxf(fmaxf(fmaxf(a[0], a[1]), fmaxf(a[2], a[3])), fmaxf(l4, l5));
        float e0 = __expf(a[0] - m), e1 = __expf(a[1] - m), e2 = __expf(a[2] - m);
        float e3 = __expf(a[3] - m), e4 = __expf(l4 - m), e5 = __expf(l5 - m);
        float inv = 1.f / (e0 + e1 + e2 + e3 + e4 + e5);
        float* sp = smb + p * SMB_STRIDE + col * 6;
        sp[0] = e0 * inv; sp[1] = e1 * inv; sp[2] = e2 * inv;
        sp[3] = e3 * inv; sp[4] = e4 * inv; sp[5] = e5 * inv;
      }
    };
    #pragma unroll
    for (int p = 0; p < 25; ++p) {
      const int py = p / 5, pxx = p % 5;
      f32x4 ae = biasl, ao = {0.f, 0.f, 0.f, 0.f};
      #pragma unroll
      for (int dy = -1; dy <= 1; ++dy)
        #pragma unroll
        for (int dx = -1; dx <= 1; ++dx)
          if ((unsigned)(py + dy) < 5u && (unsigned)(pxx + dx) < 5u) {
            const int t = (dy + 1) * 3 + (dx + 1);
            const int q = p + dy * 5 + dx;
            if (t & 1)
              ao = __builtin_amdgcn_mfma_f32_16x16x32_bf16(A[t], Y[q], ao, 0, 0, 0);
            else
              ae = __builtin_amdgcn_mfma_f32_16x16x32_bf16(A[t], Y[q], ae, 0, 0, 0);
          }
      if (p > 0) tail(pa, p - 1);          // softmax for PREVIOUS pixel
      f32x4 a;
      a[0] = ae[0] + ao[0]; a[1] = ae[1] + ao[1];
      a[2] = ae[2] + ao[2]; a[3] = ae[3] + ao[3];
      pa = a;
    }
    tail(pa, 24);
  }
  __asm__ volatile("s_waitcnt lgkmcnt(0)" ::: "memory");

  // ---- mix + store: out[b][c][p] = sum_w colors[b][c*6+w] * sm[p][b][w] ----
  for (int e = lane; e < 1200; e += 64) {
    int b = e / 75, r = e % 75, c = r / 25, p = r % 25;
    float v = 0.f;
    #pragma unroll
    for (int w = 0; w < 6; ++w)
      v = fmaf(colb[b * 18 + c * 6 + w], smb[p * SMB_STRIDE + b * 6 + w], v);
    const long oidx = g * 1200 + e;
    if (f32m) ((float*)out)[oidx] = v;
    else      ((unsigned short*)out)[oidx] = f2b(v);
  }
}

extern "C" void kernel_launch(void* const* d_in, const int* in_sizes, int n_in,
                              void* d_out, int out_size, void* d_ws, size_t ws_size,
                              hipStream_t stream) {
  unsigned short* wsb = (unsigned short*)d_ws;
  float* wsf = (float*)((char*)d_ws + WSF_BYTE);
  const int B = in_sizes[0] / 200;  // 32768

  const int prep_n = WSB_N + WSB_EMB + 288;  // 80160
  prep_weights<<<(prep_n + 255) / 256, 256, 0, stream>>>(
      d_in[1], d_in[2], d_in[3], d_in[4], d_in[5], d_in[6], d_in[7], d_in[8],
      wsb, wsf);
  pcnn_mfma<<<B / 16, 64, 0, stream>>>(d_in[0], d_in[1], wsb, wsf, d_out);
}